// Round 4
// baseline (199.167 us; speedup 1.0000x reference)
//
#include <hip/hip_runtime.h>
#include <hip/hip_bf16.h>

// CombinedGeomAttention, ALPHA=1:
//   s = 0.125*sqrt(relu(|q|^2|k|^2 - (q.k)^2) + 1e-8); out0 = softmax_s(s) @ V; out1 = mean(s)
// Round 4: swapped QK^T (lane owns 4 consecutive s for one q-row -> float4 kn,
// scalar qn2/lsum, cvt_pk P + ds_write_b64), QBLK=128 8-wave blocks (grid 512,
// 2 blocks/CU, 1 barrier/tile, K+V double-buffered), LDS-free V prepass.

#define B_ 4
#define L_ 2048
#define S_ 2048
#define H_ 8
#define E_ 64
#define EPS_ 1e-8f
#define SC2_ 0.18033688011112042f   // 0.125 * log2(e)
#define LN2_ 0.6931471805599453f
#define LDP 72
#define ROWSTR (H_ * E_)            // 512 floats

#define K_OFF 0
#define V_OFF 8388608
#define KN_OFF 16777216
#define SS_OFF 17039360
#define WS_NEED 17039364

typedef __attribute__((ext_vector_type(8))) short bf16x8;
typedef __attribute__((ext_vector_type(4))) short bf16x4v;
typedef __attribute__((ext_vector_type(4))) float f32x4;

union bfr8 { bf16x8 v; unsigned u[4]; };

static __device__ __forceinline__ unsigned pk2(float lo, float hi) {
  union { __hip_bfloat162 h2; unsigned u; } cv;
  cv.h2 = __float22bfloat162_rn(float2{lo, hi});
  return cv.u;
}
static __device__ __forceinline__ unsigned cvtpk(float lo, float hi) {
  unsigned r;
  asm("v_cvt_pk_bf16_f32 %0, %1, %2" : "=v"(r) : "v"(lo), "v"(hi));
  return r;   // D[15:0]=bf16(lo), D[31:16]=bf16(hi)
}
static __device__ __forceinline__ short f2bf_rne(float x) {
  union { float f; unsigned u; } v; v.f = x;
  unsigned r = (v.u + 0x7FFF + ((v.u >> 16) & 1)) >> 16;
  return (short)(unsigned short)r;
}
static __device__ __forceinline__ float bf2f(short h) {
  union { unsigned u; float f; } v; v.u = ((unsigned)(unsigned short)h) << 16;
  return v.f;
}
static __device__ __forceinline__ float fast_sqrt(float x) {
  float r; asm("v_sqrt_f32 %0, %1" : "=v"(r) : "v"(x)); return r;
}
static __device__ __forceinline__ float fast_exp2(float x) {
  float r; asm("v_exp_f32 %0, %1" : "=v"(r) : "v"(x)); return r;
}
static __device__ __forceinline__ void gload16(const void* g, void* l) {
  __builtin_amdgcn_global_load_lds((const __attribute__((address_space(1))) void*)g,
                                   (__attribute__((address_space(3))) void*)l, 16, 0, 0);
}

// ---------------- fused prepass ----------------
// blocks 0..1023:    K -> bf16 swizzled [bh,tile][s][e-chunks] + |k|^2
// blocks 1024..2047: V -> bf16 transposed+swizzled [bh,tile][e][s-chunks] (no LDS)
__global__ void prep_kv(const float* __restrict__ K, const float* __restrict__ V,
                        short* __restrict__ Kg, short* __restrict__ Vg,
                        float* __restrict__ kn2g) {
  const int tid = threadIdx.x;
  const int raw = blockIdx.x;
  const bool isK = raw < 1024;
  const int bidx = isK ? raw : raw - 1024;
  const int st = bidx & 31;
  const int bh = bidx >> 5;
  const int b = bh >> 3, h = bh & 7;
  const size_t src_base = (size_t)b * (L_ * ROWSTR) + (size_t)(st * 64) * ROWSTR + (size_t)h * E_;

  if (isK) {
    short* dst = Kg + (size_t)bidx * 4096;
    const int s = tid >> 2;
    float part = 0.f;
#pragma unroll
    for (int q = 0; q < 2; ++q) {
      const int ch = (2 * tid + q) & 7;
      const int esrc = (ch ^ (s & 7)) * 8;
      const float* sp = K + src_base + (size_t)s * ROWSTR + esrc;
      const float4 a = *reinterpret_cast<const float4*>(sp);
      const float4 c4 = *reinterpret_cast<const float4*>(sp + 4);
      part += a.x*a.x + a.y*a.y + a.z*a.z + a.w*a.w
            + c4.x*c4.x + c4.y*c4.y + c4.z*c4.z + c4.w*c4.w;
      bfr8 o;
      o.u[0] = pk2(a.x, a.y);  o.u[1] = pk2(a.z, a.w);
      o.u[2] = pk2(c4.x, c4.y); o.u[3] = pk2(c4.z, c4.w);
      *reinterpret_cast<bf16x8*>(dst + s * 64 + ch * 8) = o.v;
    }
    part += __shfl_xor(part, 1);
    part += __shfl_xor(part, 2);
    if ((tid & 3) == 0) kn2g[(size_t)bidx * 64 + s] = part;
  } else {
    // V transpose without LDS: lane e, s-chunk sc; coalesced column reads.
    short* dst = Vg + (size_t)bidx * 4096;
    const int e = tid & 63;
    const int sc0 = tid >> 6;       // 0..3; handles sc0 and sc0+4
#pragma unroll
    for (int q = 0; q < 2; ++q) {
      const int sc = sc0 + q * 4;
      const float* sp = V + src_base + (size_t)(sc * 8) * ROWSTR + e;
      float v0 = sp[0];
      float v1 = sp[1 * ROWSTR];
      float v2 = sp[2 * ROWSTR];
      float v3 = sp[3 * ROWSTR];
      float v4 = sp[4 * ROWSTR];
      float v5 = sp[5 * ROWSTR];
      float v6 = sp[6 * ROWSTR];
      float v7 = sp[7 * ROWSTR];
      bfr8 o;
      o.u[0] = pk2(v0, v1); o.u[1] = pk2(v2, v3);
      o.u[2] = pk2(v4, v5); o.u[3] = pk2(v6, v7);
      *reinterpret_cast<bf16x8*>(dst + e * 64 + ((sc ^ (e & 7)) * 8)) = o.v;
    }
  }
}

// ---------------- main attention ----------------
__launch_bounds__(512, 4)
__global__ void geom_attn(const float* __restrict__ Q,
                          const short* __restrict__ Kg,
                          const short* __restrict__ Vg,
                          const float* __restrict__ kn2g,
                          float* __restrict__ out,
                          float* __restrict__ ssum_g) {
  __shared__ __align__(16) short Kl[2][4096];
  __shared__ __align__(16) short Vl[2][4096];
  __shared__ __align__(16) short Plds[8][16 * LDP];

  const int tid = threadIdx.x;
  const int lane = tid & 63;
  const int w = tid >> 6;       // 0..7
  const int g = lane >> 4;      // 0..3
  const int c = lane & 15;
  const int cx = c & 7;

  // XCD-chunked swizzle: 512 blocks, 8 XCDs; each XCD owns 4 consecutive bh (2MB K/V in L2)
  const int vbk = ((blockIdx.x & 7) << 6) + (blockIdx.x >> 3);
  const int qt = vbk & 15;
  const int bh = vbk >> 4;
  const int b = bh >> 3, h = bh & 7;
  const int q0 = qt * 128;

  const size_t qbase = (size_t)b * (L_ * ROWSTR) + (size_t)h * E_;

  // ---- Q fragments (bf16 pairs) + |q|^2 (fp32 exact); lane ends with qn2 of row c
  bfr8 qa[2];
  float qn2sc;
  {
    const int qrow = q0 + w * 16 + c;
    const float* qp = Q + qbase + (size_t)qrow * ROWSTR;
    float qs = 0.f;
#pragma unroll
    for (int ch = 0; ch < 2; ++ch) {
      const float4 a = *reinterpret_cast<const float4*>(qp + ch * 32 + g * 8);
      const float4 b4 = *reinterpret_cast<const float4*>(qp + ch * 32 + g * 8 + 4);
      qa[ch].u[0] = pk2(a.x, a.y);  qa[ch].u[1] = pk2(a.z, a.w);
      qa[ch].u[2] = pk2(b4.x, b4.y); qa[ch].u[3] = pk2(b4.z, b4.w);
      qs += a.x*a.x + a.y*a.y + a.z*a.z + a.w*a.w
          + b4.x*b4.x + b4.y*b4.y + b4.z*b4.z + b4.w*b4.w;
    }
    qs += __shfl_xor(qs, 16);
    qs += __shfl_xor(qs, 32);
    qn2sc = qs;                    // |q|^2 for q-row (w*16 + c)
  }

  float lsum4[4] = {0.f, 0.f, 0.f, 0.f};   // partial row-c sum (split chains)
  float ssum4[4] = {0.f, 0.f, 0.f, 0.f};
  f32x4 o[4];
#pragma unroll
  for (int dt = 0; dt < 4; ++dt) o[dt] = (f32x4){0.f, 0.f, 0.f, 0.f};

  const char* Ksrc = (const char*)(Kg + (size_t)(bh * 32) * 4096);
  const char* Vsrc = (const char*)(Vg + (size_t)(bh * 32) * 4096);
  const float* knb = kn2g + (size_t)(bh * 32) * 64;

  float4 kn_cur[4], kn_nx[4];
#pragma unroll
  for (int sub = 0; sub < 4; ++sub)
    kn_cur[sub] = *reinterpret_cast<const float4*>(knb + sub * 16 + g * 4);

  // prologue: stage K[0],V[0] into buffer 0 (1KB per wave each)
  gload16(Ksrc + w * 1024 + lane * 16, (char*)&Kl[0][0] + w * 1024);
  gload16(Vsrc + w * 1024 + lane * 16, (char*)&Vl[0][0] + w * 1024);

  for (int kt = 0; kt < 32; ++kt) {
    const int cb = kt & 1;
    __syncthreads();   // drains vmcnt: K[kt],V[kt] staged; bufs cb^1 free

    if (kt + 1 < 32) {
      const int nx = kt + 1;
#pragma unroll
      for (int sub = 0; sub < 4; ++sub)
        kn_nx[sub] = *reinterpret_cast<const float4*>(knb + nx * 64 + sub * 16 + g * 4);
      __builtin_amdgcn_sched_barrier(0);
      gload16(Ksrc + (size_t)nx * 8192 + w * 1024 + lane * 16, (char*)&Kl[cb ^ 1][0] + w * 1024);
      gload16(Vsrc + (size_t)nx * 8192 + w * 1024 + lane * 16, (char*)&Vl[cb ^ 1][0] + w * 1024);
    }

    // ---- swapped QK^T: acc[i] = S[s = sub*16 + g*4 + i][qrow = w*16 + c]
#pragma unroll
    for (int sub = 0; sub < 4; ++sub) {
      f32x4 acc = (f32x4){0.f, 0.f, 0.f, 0.f};
#pragma unroll
      for (int ch = 0; ch < 2; ++ch) {
        const int idx = (sub * 16 + c) * 64 + (((ch * 4 + g) ^ cx) << 3);
        const bf16x8 kh8 = *reinterpret_cast<const bf16x8*>(&Kl[cb][idx]);
        acc = __builtin_amdgcn_mfma_f32_16x16x32_bf16(kh8, qa[ch].v, acc, 0, 0, 0);
      }
      const float4 kn = kn_cur[sub];
      float p[4];
#pragma unroll
      for (int i = 0; i < 4; ++i) {
        const float dot = acc[i];
        const float knv = (i == 0) ? kn.x : (i == 1) ? kn.y : (i == 2) ? kn.z : kn.w;
        const float w2 = fmaxf(fmaf(-dot, dot, fmaf(qn2sc, knv, EPS_)), EPS_);
        const float s2 = SC2_ * fast_sqrt(w2);   // score * log2(e)
        ssum4[i] += s2;
        p[i] = fast_exp2(s2);                    // exp(score)
        lsum4[i] += p[i];
      }
      uint2 pw;
      pw.x = cvtpk(p[0], p[1]);
      pw.y = cvtpk(p[2], p[3]);
      *reinterpret_cast<uint2*>(&Plds[w][c * LDP + sub * 16 + g * 4]) = pw;
    }

    // ---- PV: o[16x64] += P[16x64] @ V[64x64]  (wave-private P, no barrier)
#pragma unroll
    for (int ks = 0; ks < 2; ++ks) {
      const bf16x8 pa = *reinterpret_cast<const bf16x8*>(&Plds[w][c * LDP + ks * 32 + g * 8]);
#pragma unroll
      for (int dt = 0; dt < 4; ++dt) {
        const int idx = (dt * 16 + c) * 64 + (((ks * 4 + g) ^ cx) << 3);
        const bf16x8 vb8 = *reinterpret_cast<const bf16x8*>(&Vl[cb][idx]);
        o[dt] = __builtin_amdgcn_mfma_f32_16x16x32_bf16(pa, vb8, o[dt], 0, 0, 0);
      }
    }
#pragma unroll
    for (int sub = 0; sub < 4; ++sub) kn_cur[sub] = kn_nx[sub];
  }

  // ---- epilogue: finish row-c sum, broadcast row g*4+i's inverse, store
  float lsum = (lsum4[0] + lsum4[1]) + (lsum4[2] + lsum4[3]);
  lsum += __shfl_xor(lsum, 16);
  lsum += __shfl_xor(lsum, 32);
  const float rinv = 1.0f / lsum;   // 1/rowsum for q-row (w*16 + c)

#pragma unroll
  for (int i = 0; i < 4; ++i) {
    const float inv = __shfl(rinv, g * 4 + i);   // lane g*4+i holds row g*4+i
    const int qrow = q0 + w * 16 + g * 4 + i;
    float* op = out + (size_t)b * (L_ * ROWSTR) + (size_t)qrow * ROWSTR + (size_t)h * E_;
#pragma unroll
    for (int dt = 0; dt < 4; ++dt)
      op[dt * 16 + c] = o[dt][i] * inv;
  }

  float ssum = (ssum4[0] + ssum4[1]) + (ssum4[2] + ssum4[3]);
#pragma unroll
  for (int m = 1; m < 64; m <<= 1) ssum += __shfl_xor(ssum, m);
  if (lane == 0) atomicAdd(ssum_g, ssum);
}

__global__ void geom_fin(const float* __restrict__ ws, float* __restrict__ out) {
  out[(size_t)B_ * L_ * H_ * E_] = ws[0] * (LN2_ / 134217728.0f);
}

// ================= fallback (round-1 kernel) if ws too small =================
__launch_bounds__(256, 2)
__global__ void geom_attn_v1(const float* __restrict__ Q, const float* __restrict__ K,
                             const float* __restrict__ V, float* __restrict__ out,
                             float* __restrict__ score_sum) {
  __shared__ __align__(16) short Khi[64 * LDP];
  __shared__ __align__(16) short Klo[64 * LDP];
  __shared__ __align__(16) short Vt[64 * LDP];
  __shared__ __align__(16) short Plds[4][16 * LDP];
  __shared__ float kn2[64];
  __shared__ float qn2[64];

  const int tid = threadIdx.x;
  const int lane = tid & 63;
  const int w = tid >> 6;
  const int g = lane >> 4;
  const int c = lane & 15;
  const int bidx = blockIdx.x;
  const int qt = bidx & 31;
  const int h = (bidx >> 5) & 7;
  const int b = bidx >> 8;
  const int q0 = qt * 64;
  const size_t bh_base = (size_t)b * L_ * ROWSTR + (size_t)h * E_;

  bf16x8 qhi[2], qlo[2];
  {
    const int qrow = q0 + w * 16 + c;
    const float* qp = Q + bh_base + (size_t)qrow * ROWSTR;
    float qs = 0.f;
#pragma unroll
    for (int ch = 0; ch < 2; ++ch) {
      const float4 a = *reinterpret_cast<const float4*>(qp + ch * 32 + g * 8);
      const float4 bq = *reinterpret_cast<const float4*>(qp + ch * 32 + g * 8 + 4);
      const float xs[8] = {a.x,a.y,a.z,a.w,bq.x,bq.y,bq.z,bq.w};
#pragma unroll
      for (int j = 0; j < 8; ++j) {
        const float x = xs[j];
        qs += x * x;
        const short hs = f2bf_rne(x);
        qhi[ch][j] = hs;
        qlo[ch][j] = f2bf_rne(x - bf2f(hs));
      }
    }
    qs += __shfl_xor(qs, 16);
    qs += __shfl_xor(qs, 32);
    if (lane < 16) qn2[w * 16 + c] = qs;
  }
  __syncthreads();
  float qn2row[4];
#pragma unroll
  for (int i = 0; i < 4; ++i) qn2row[i] = qn2[w * 16 + g * 4 + i];

  float m_i[4] = {0,0,0,0}, lsum[4] = {0,0,0,0};
  f32x4 o[4];
#pragma unroll
  for (int dt = 0; dt < 4; ++dt) o[dt] = (f32x4){0,0,0,0};
  float ssum = 0.f;

  for (int kt = 0; kt < S_ / 64; ++kt) {
    __syncthreads();
    {
      const int r0 = tid >> 4, c4 = tid & 15;
      const size_t kbase = bh_base + (size_t)(kt * 64) * ROWSTR + c4 * 4;
      float part[4];
#pragma unroll
      for (int i = 0; i < 4; ++i) {
        const int r = r0 + 16 * i;
        const float4 kv = *reinterpret_cast<const float4*>(K + kbase + (size_t)r * ROWSTR);
        part[i] = kv.x*kv.x + kv.y*kv.y + kv.z*kv.z + kv.w*kv.w;
        const short h0 = f2bf_rne(kv.x), h1 = f2bf_rne(kv.y), h2 = f2bf_rne(kv.z), h3 = f2bf_rne(kv.w);
        bf16x4v hv = {h0, h1, h2, h3};
        *reinterpret_cast<bf16x4v*>(&Khi[r * LDP + c4 * 4]) = hv;
        bf16x4v lv = {f2bf_rne(kv.x - bf2f(h0)), f2bf_rne(kv.y - bf2f(h1)),
                      f2bf_rne(kv.z - bf2f(h2)), f2bf_rne(kv.w - bf2f(h3))};
        *reinterpret_cast<bf16x4v*>(&Klo[r * LDP + c4 * 4]) = lv;
        const float4 vv = *reinterpret_cast<const float4*>(V + kbase + (size_t)r * ROWSTR);
        Vt[(c4 * 4 + 0) * LDP + r] = f2bf_rne(vv.x);
        Vt[(c4 * 4 + 1) * LDP + r] = f2bf_rne(vv.y);
        Vt[(c4 * 4 + 2) * LDP + r] = f2bf_rne(vv.z);
        Vt[(c4 * 4 + 3) * LDP + r] = f2bf_rne(vv.w);
      }
#pragma unroll
      for (int m = 1; m < 16; m <<= 1)
#pragma unroll
        for (int i = 0; i < 4; ++i) part[i] += __shfl_xor(part[i], m);
      if (c4 < 4) kn2[r0 + 16 * c4] = part[c4];
    }
    __syncthreads();

    float sv[4][4];
    float tm[4] = {0,0,0,0};
#pragma unroll
    for (int sub = 0; sub < 4; ++sub) {
      const int s = sub * 16 + c;
      f32x4 acc = (f32x4){0,0,0,0};
#pragma unroll
      for (int ch = 0; ch < 2; ++ch) {
        const int e = ch * 32 + g * 8;
        const bf16x8 bh8 = *reinterpret_cast<const bf16x8*>(&Khi[s * LDP + e]);
        const bf16x8 bl8 = *reinterpret_cast<const bf16x8*>(&Klo[s * LDP + e]);
        acc = __builtin_amdgcn_mfma_f32_16x16x32_bf16(qhi[ch], bh8, acc, 0, 0, 0);
        acc = __builtin_amdgcn_mfma_f32_16x16x32_bf16(qlo[ch], bh8, acc, 0, 0, 0);
        acc = __builtin_amdgcn_mfma_f32_16x16x32_bf16(qhi[ch], bl8, acc, 0, 0, 0);
      }
      const float kn = kn2[s];
#pragma unroll
      for (int i = 0; i < 4; ++i) {
        const float dot = acc[i];
        float w2 = fmaxf(qn2row[i] * kn - dot * dot, 0.f) + EPS_;
        const float sc = 0.125f * sqrtf(w2);
        sv[sub][i] = sc;
        tm[i] = fmaxf(tm[i], sc);
        ssum += sc;
      }
    }
#pragma unroll
    for (int m = 1; m < 16; m <<= 1)
#pragma unroll
      for (int i = 0; i < 4; ++i) tm[i] = fmaxf(tm[i], __shfl_xor(tm[i], m));
    float r_[4];
#pragma unroll
    for (int i = 0; i < 4; ++i) {
      const float mn = fmaxf(m_i[i], tm[i]);
      r_[i] = __expf(m_i[i] - mn);
      m_i[i] = mn;
      lsum[i] *= r_[i];
    }
#pragma unroll
    for (int dt = 0; dt < 4; ++dt)
#pragma unroll
      for (int i = 0; i < 4; ++i) o[dt][i] *= r_[i];
#pragma unroll
    for (int sub = 0; sub < 4; ++sub) {
      const int s = sub * 16 + c;
#pragma unroll
      for (int i = 0; i < 4; ++i) {
        const float p = __expf(sv[sub][i] - m_i[i]);
        lsum[i] += p;
        Plds[w][(g * 4 + i) * LDP + s] = f2bf_rne(p);
      }
    }
    __syncthreads();
#pragma unroll
    for (int ks = 0; ks < 2; ++ks) {
      const bf16x8 pa = *reinterpret_cast<const bf16x8*>(&Plds[w][c * LDP + ks * 32 + g * 8]);
#pragma unroll
      for (int dt = 0; dt < 4; ++dt) {
        const bf16x8 vb8 = *reinterpret_cast<const bf16x8*>(&Vt[(dt * 16 + c) * LDP + ks * 32 + g * 8]);
        o[dt] = __builtin_amdgcn_mfma_f32_16x16x32_bf16(pa, vb8, o[dt], 0, 0, 0);
      }
    }
  }
#pragma unroll
  for (int m = 1; m < 16; m <<= 1)
#pragma unroll
    for (int i = 0; i < 4; ++i) lsum[i] += __shfl_xor(lsum[i], m);
#pragma unroll
  for (int i = 0; i < 4; ++i) {
    const float inv = 1.0f / lsum[i];
    const int qrow = q0 + w * 16 + g * 4 + i;
    float* op = out + (size_t)b * L_ * ROWSTR + (size_t)qrow * ROWSTR + (size_t)h * E_;
#pragma unroll
    for (int dt = 0; dt < 4; ++dt) op[dt * 16 + c] = o[dt][i] * inv;
  }
#pragma unroll
  for (int m = 1; m < 64; m <<= 1) ssum += __shfl_xor(ssum, m);
  if (lane == 0) atomicAdd(score_sum, ssum);
}

__global__ void geom_fin_v1(const float* __restrict__ ws, float* __restrict__ out) {
  out[(size_t)B_ * L_ * H_ * E_] = ws[0] * (1.0f / 134217728.0f);
}

extern "C" void kernel_launch(void* const* d_in, const int* in_sizes, int n_in,
                              void* d_out, int out_size, void* d_ws, size_t ws_size,
                              hipStream_t stream) {
  const float* Q = (const float*)d_in[0];
  const float* K = (const float*)d_in[1];
  const float* V = (const float*)d_in[2];
  float* out = (float*)d_out;

  if (ws_size >= (size_t)WS_NEED) {
    short* Kg = (short*)((char*)d_ws + K_OFF);
    short* Vg = (short*)((char*)d_ws + V_OFF);
    float* kn2g = (float*)((char*)d_ws + KN_OFF);
    float* ss = (float*)((char*)d_ws + SS_OFF);
    hipMemsetAsync(ss, 0, sizeof(float), stream);
    prep_kv<<<dim3(2048), dim3(256), 0, stream>>>(K, V, Kg, Vg, kn2g);
    geom_attn<<<dim3(512), dim3(512), 0, stream>>>(Q, Kg, Vg, kn2g, out, ss);
    geom_fin<<<dim3(1), dim3(1), 0, stream>>>(ss, out);
  } else {
    float* ss = (float*)d_ws;
    hipMemsetAsync(ss, 0, sizeof(float), stream);
    geom_attn_v1<<<dim3(1024), dim3(256), 0, stream>>>(Q, K, V, out, ss);
    geom_fin_v1<<<dim3(1), dim3(1), 0, stream>>>(ss, out);
  }
}

// Round 5
// 192.340 us; speedup vs baseline: 1.0355x; 1.0355x over previous
//
#include <hip/hip_runtime.h>
#include <hip/hip_bf16.h>

// CombinedGeomAttention, ALPHA=1:
//   s = 0.125*sqrt(relu(|q|^2|k|^2 - (q.k)^2) + 1e-8); out0 = softmax_s(s) @ V; out1 = mean(s)
// Round 5: round-3 shape (QBLK=64, 256thr, grid 1024, K dbuf + V single-buf +
// counted-vmcnt mid barrier) + swapped-QK cheap score path + packed-f32 score
// math + 32KB LDS (swizzled unpadded P) + setprio(PV) + fused prep + no fin kernel.

#define B_ 4
#define L_ 2048
#define S_ 2048
#define H_ 8
#define E_ 64
#define EPS_ 1e-8f
#define SC2_ 0.18033688011112042f   // 0.125 * log2(e)
#define LN2_ 0.6931471805599453f
#define ROWSTR (H_ * E_)            // 512 floats
#define NOUT ((size_t)B_ * L_ * H_ * E_)

#define K_OFF 0
#define V_OFF 8388608
#define KN_OFF 16777216
#define WS_NEED 17039360

typedef __attribute__((ext_vector_type(8))) short bf16x8;
typedef __attribute__((ext_vector_type(4))) float f32x4;
typedef __attribute__((ext_vector_type(2))) float f32x2;

union bfr8 { bf16x8 v; unsigned u[4]; };

static __device__ __forceinline__ unsigned pk2(float lo, float hi) {
  union { __hip_bfloat162 h2; unsigned u; } cv;
  cv.h2 = __float22bfloat162_rn(float2{lo, hi});
  return cv.u;
}
static __device__ __forceinline__ unsigned cvtpk(float lo, float hi) {
  unsigned r;
  asm("v_cvt_pk_bf16_f32 %0, %1, %2" : "=v"(r) : "v"(lo), "v"(hi));
  return r;
}
static __device__ __forceinline__ float fast_sqrt(float x) {
  float r; asm("v_sqrt_f32 %0, %1" : "=v"(r) : "v"(x)); return r;
}
static __device__ __forceinline__ float fast_exp2(float x) {
  float r; asm("v_exp_f32 %0, %1" : "=v"(r) : "v"(x)); return r;
}
static __device__ __forceinline__ void gload16(const void* g, void* l) {
  __builtin_amdgcn_global_load_lds((const __attribute__((address_space(1))) void*)g,
                                   (__attribute__((address_space(3))) void*)l, 16, 0, 0);
}

// ---------------- fused prepass: one block = one (bh, s-tile); does K AND V ----------------
// K -> bf16 swizzled [bh,tile][s][e-chunks] + |k|^2 ; V -> bf16 transposed+swizzled [e][s-chunks]
__global__ void prep_kv(const float* __restrict__ K, const float* __restrict__ V,
                        short* __restrict__ Kg, short* __restrict__ Vg,
                        float* __restrict__ kn2g) {
  const int tid = threadIdx.x;
  const int bidx = blockIdx.x;          // bh*32 + st
  const int st = bidx & 31;
  const int bh = bidx >> 5;
  const int b = bh >> 3, h = bh & 7;
  const size_t src_base = (size_t)b * (L_ * ROWSTR) + (size_t)(st * 64) * ROWSTR + (size_t)h * E_;

  // ---- K part
  {
    short* dst = Kg + (size_t)bidx * 4096;
    const int s = tid >> 2;
    float part = 0.f;
#pragma unroll
    for (int q = 0; q < 2; ++q) {
      const int ch = (2 * tid + q) & 7;
      const int esrc = (ch ^ (s & 7)) * 8;
      const float* sp = K + src_base + (size_t)s * ROWSTR + esrc;
      const float4 a = *reinterpret_cast<const float4*>(sp);
      const float4 c4 = *reinterpret_cast<const float4*>(sp + 4);
      part += a.x*a.x + a.y*a.y + a.z*a.z + a.w*a.w
            + c4.x*c4.x + c4.y*c4.y + c4.z*c4.z + c4.w*c4.w;
      bfr8 o;
      o.u[0] = pk2(a.x, a.y);  o.u[1] = pk2(a.z, a.w);
      o.u[2] = pk2(c4.x, c4.y); o.u[3] = pk2(c4.z, c4.w);
      *reinterpret_cast<bf16x8*>(dst + s * 64 + ch * 8) = o.v;
    }
    part += __shfl_xor(part, 1);
    part += __shfl_xor(part, 2);
    if ((tid & 3) == 0) kn2g[(size_t)bidx * 64 + s] = part;
  }

  // ---- V part (no LDS; coalesced 256B column-segment reads)
  {
    short* dst = Vg + (size_t)bidx * 4096;
    const int e = tid & 63;
    const int sc0 = tid >> 6;       // 0..3; handles sc0 and sc0+4
#pragma unroll
    for (int q = 0; q < 2; ++q) {
      const int sc = sc0 + q * 4;
      const float* sp = V + src_base + (size_t)(sc * 8) * ROWSTR + e;
      const float v0 = sp[0];
      const float v1 = sp[1 * ROWSTR];
      const float v2 = sp[2 * ROWSTR];
      const float v3 = sp[3 * ROWSTR];
      const float v4 = sp[4 * ROWSTR];
      const float v5 = sp[5 * ROWSTR];
      const float v6 = sp[6 * ROWSTR];
      const float v7 = sp[7 * ROWSTR];
      bfr8 o;
      o.u[0] = pk2(v0, v1); o.u[1] = pk2(v2, v3);
      o.u[2] = pk2(v4, v5); o.u[3] = pk2(v6, v7);
      *reinterpret_cast<bf16x8*>(dst + e * 64 + ((sc ^ (e & 7)) * 8)) = o.v;
    }
  }
}

// ---------------- main attention ----------------
__launch_bounds__(256, 4)
__global__ void geom_attn(const float* __restrict__ Q,
                          const short* __restrict__ Kg,
                          const short* __restrict__ Vg,
                          const float* __restrict__ kn2g,
                          float* __restrict__ out) {
  __shared__ __align__(16) short Kl[2][4096];   // 16 KB
  __shared__ __align__(16) short Vl[4096];      //  8 KB
  __shared__ __align__(16) short Plds[4][2048]; //  8 KB (swizzled, unpadded)

  const int tid = threadIdx.x;
  const int lane = tid & 63;
  const int w = tid >> 6;       // 0..3
  const int g = lane >> 4;      // 0..3
  const int c = lane & 15;
  const int cx = c & 7;

  // XCD-chunked swizzle: 1024 blocks; each XCD owns 4 consecutive bh (K/V ~2MB in its L2)
  const int vbk = ((blockIdx.x & 7) << 7) + (blockIdx.x >> 3);
  const int qt = vbk & 31;
  const int bh = vbk >> 5;
  const int b = bh >> 3, h = bh & 7;
  const int q0 = qt * 64;

  const size_t qbase = (size_t)b * (L_ * ROWSTR) + (size_t)h * E_;

  // ---- Q fragments (bf16 pairs) + |q|^2 (fp32 exact); lane holds qn2 of q-row w*16+c
  bfr8 qa[2];
  float qn2sc;
  {
    const int qrow = q0 + w * 16 + c;
    const float* qp = Q + qbase + (size_t)qrow * ROWSTR;
    float qs = 0.f;
#pragma unroll
    for (int ch = 0; ch < 2; ++ch) {
      const float4 a = *reinterpret_cast<const float4*>(qp + ch * 32 + g * 8);
      const float4 b4 = *reinterpret_cast<const float4*>(qp + ch * 32 + g * 8 + 4);
      qa[ch].u[0] = pk2(a.x, a.y);  qa[ch].u[1] = pk2(a.z, a.w);
      qa[ch].u[2] = pk2(b4.x, b4.y); qa[ch].u[3] = pk2(b4.z, b4.w);
      qs += a.x*a.x + a.y*a.y + a.z*a.z + a.w*a.w
          + b4.x*b4.x + b4.y*b4.y + b4.z*b4.z + b4.w*b4.w;
    }
    qs += __shfl_xor(qs, 16);
    qs += __shfl_xor(qs, 32);
    qn2sc = qs;
  }
  const f32x2 qn2v = {qn2sc, qn2sc};
  const f32x2 eps2 = {EPS_, EPS_};
  const f32x2 sc2v = {SC2_, SC2_};

  f32x2 lsA = {0.f, 0.f}, lsB = {0.f, 0.f};   // softmax denom partials (i01 / i23)
  f32x2 ssA = {0.f, 0.f}, ssB = {0.f, 0.f};   // score-sum partials
  f32x4 o[4];
#pragma unroll
  for (int dt = 0; dt < 4; ++dt) o[dt] = (f32x4){0.f, 0.f, 0.f, 0.f};

  const char* Ksrc = (const char*)(Kg + (size_t)(bh * 32) * 4096);
  const char* Vsrc = (const char*)(Vg + (size_t)(bh * 32) * 4096);
  const float* knb = kn2g + (size_t)(bh * 32) * 64;

  const int wb = w * 2048;  // wave's byte range within an 8KB tile

  f32x4 kn_cur[4], kn_nx[4];
#pragma unroll
  for (int sub = 0; sub < 4; ++sub)
    kn_cur[sub] = *reinterpret_cast<const f32x4*>(knb + sub * 16 + g * 4);

  // prologue: stage K[0]
  gload16(Ksrc + wb + lane * 16,        (char*)&Kl[0][0] + wb);
  gload16(Ksrc + wb + 1024 + lane * 16, (char*)&Kl[0][0] + wb + 1024);

  for (int kt = 0; kt < 32; ++kt) {
    const int cb = kt & 1;
    const int nx = (kt + 1) & 31;     // wrap: harmless extra prefetch on last iter
    __syncthreads();   // vmcnt(0): K[kt] staged; Vl free (PV kt-1 done); Kl[cb^1] free

    // (1) kn prefetch FIRST so vmcnt(2) below drains it, not K[nx]
#pragma unroll
    for (int sub = 0; sub < 4; ++sub)
      kn_nx[sub] = *reinterpret_cast<const f32x4*>(knb + nx * 64 + sub * 16 + g * 4);
    __builtin_amdgcn_sched_barrier(0);
    // (2) V[kt] -> Vl (single buffer)
    const char* vs = Vsrc + (size_t)kt * 8192;
    gload16(vs + wb + lane * 16,        (char*)&Vl[0] + wb);
    gload16(vs + wb + 1024 + lane * 16, (char*)&Vl[0] + wb + 1024);
    // (3) K[nx] -> other K buffer (stays in flight across the counted barrier)
    const char* ks = Ksrc + (size_t)nx * 8192;
    gload16(ks + wb + lane * 16,        (char*)&Kl[cb ^ 1][0] + wb);
    gload16(ks + wb + 1024 + lane * 16, (char*)&Kl[cb ^ 1][0] + wb + 1024);

    // ---- swapped QK^T: acc[i] = S[s = sub*16 + g*4 + i][qrow = w*16 + c]
#pragma unroll
    for (int sub = 0; sub < 4; ++sub) {
      f32x4 acc = (f32x4){0.f, 0.f, 0.f, 0.f};
#pragma unroll
      for (int ch = 0; ch < 2; ++ch) {
        const int idx = (sub * 16 + c) * 64 + (((ch * 4 + g) ^ cx) << 3);
        const bf16x8 kh8 = *reinterpret_cast<const bf16x8*>(&Kl[cb][idx]);
        acc = __builtin_amdgcn_mfma_f32_16x16x32_bf16(kh8, qa[ch].v, acc, 0, 0, 0);
      }
      // packed-f32 score math (f32x2 -> v_pk_* on gfx950)
      const f32x2 d0 = {acc[0], acc[1]};
      const f32x2 d1 = {acc[2], acc[3]};
      const f32x2 ka = {kn_cur[sub][0], kn_cur[sub][1]};
      const f32x2 kb = {kn_cur[sub][2], kn_cur[sub][3]};
      f32x2 w0 = -d0 * d0 + (qn2v * ka + eps2);
      f32x2 w1 = -d1 * d1 + (qn2v * kb + eps2);
      w0[0] = fmaxf(w0[0], EPS_); w0[1] = fmaxf(w0[1], EPS_);
      w1[0] = fmaxf(w1[0], EPS_); w1[1] = fmaxf(w1[1], EPS_);
      f32x2 s0 = {fast_sqrt(w0[0]), fast_sqrt(w0[1])};
      f32x2 s1 = {fast_sqrt(w1[0]), fast_sqrt(w1[1])};
      s0 *= sc2v; s1 *= sc2v;
      ssA += s0; ssB += s1;
      const f32x2 p0 = {fast_exp2(s0[0]), fast_exp2(s0[1])};
      const f32x2 p1 = {fast_exp2(s1[0]), fast_exp2(s1[1])};
      lsA += p0; lsB += p1;
      uint2 pw;
      pw.x = cvtpk(p0[0], p0[1]);
      pw.y = cvtpk(p1[0], p1[1]);
      // swizzled P store: row c (q), inner shorts (sub*16+g*4) ^ (cx<<3)
      const int po = c * 128 + ((sub * 16 + g * 4) ^ (cx << 3));
      *reinterpret_cast<uint2*>(&Plds[w][po]) = pw;
    }

    // counted-vmcnt barrier: kn(4)+V(2) drained, K[nx](2) still flying
    asm volatile("s_waitcnt vmcnt(2)\n\ts_barrier" ::: "memory");

    // ---- PV: o[16x64] += P[16x64] @ V[64x64]
    __builtin_amdgcn_s_setprio(1);
#pragma unroll
    for (int ks2 = 0; ks2 < 2; ++ks2) {
      const int pr = c * 128 + ((ks2 * 32 + g * 8) ^ (cx << 3));
      const bf16x8 pa = *reinterpret_cast<const bf16x8*>(&Plds[w][pr]);
#pragma unroll
      for (int dt = 0; dt < 4; ++dt) {
        const int idx = (dt * 16 + c) * 64 + (((ks2 * 4 + g) ^ cx) << 3);
        const bf16x8 vb8 = *reinterpret_cast<const bf16x8*>(&Vl[idx]);
        o[dt] = __builtin_amdgcn_mfma_f32_16x16x32_bf16(pa, vb8, o[dt], 0, 0, 0);
      }
    }
    __builtin_amdgcn_s_setprio(0);
#pragma unroll
    for (int sub = 0; sub < 4; ++sub) kn_cur[sub] = kn_nx[sub];
  }

  // ---- epilogue: finish row-c sum, broadcast row g*4+i's inverse, store
  const f32x2 lsT = lsA + lsB;
  float lsum = lsT[0] + lsT[1];
  lsum += __shfl_xor(lsum, 16);
  lsum += __shfl_xor(lsum, 32);
  const float rinv = 1.0f / lsum;   // 1/rowsum for q-row (w*16 + c)

#pragma unroll
  for (int i = 0; i < 4; ++i) {
    const float inv = __shfl(rinv, g * 4 + i);   // lane g*4+i holds row g*4+i
    const int qrow = q0 + w * 16 + g * 4 + i;
    float* op = out + (size_t)b * (L_ * ROWSTR) + (size_t)qrow * ROWSTR + (size_t)h * E_;
#pragma unroll
    for (int dt = 0; dt < 4; ++dt)
      op[dt * 16 + c] = o[dt][i] * inv;
  }

  const f32x2 ssT = ssA + ssB;
  float ssum = ssT[0] + ssT[1];
#pragma unroll
  for (int m = 1; m < 64; m <<= 1) ssum += __shfl_xor(ssum, m);
  if (lane == 0) atomicAdd(out + NOUT, ssum * (LN2_ / 134217728.0f));
}

extern "C" void kernel_launch(void* const* d_in, const int* in_sizes, int n_in,
                              void* d_out, int out_size, void* d_ws, size_t ws_size,
                              hipStream_t stream) {
  const float* Q = (const float*)d_in[0];
  const float* K = (const float*)d_in[1];
  const float* V = (const float*)d_in[2];
  float* out = (float*)d_out;

  short* Kg = (short*)((char*)d_ws + K_OFF);
  short* Vg = (short*)((char*)d_ws + V_OFF);
  float* kn2g = (float*)((char*)d_ws + KN_OFF);

  hipMemsetAsync(out + NOUT, 0, sizeof(float), stream);  // zero the scalar slot (atomic target)
  prep_kv<<<dim3(1024), dim3(256), 0, stream>>>(K, V, Kg, Vg, kn2g);
  geom_attn<<<dim3(1024), dim3(256), 0, stream>>>(Q, Kg, Vg, kn2g, out);
}

// Round 6
// 189.428 us; speedup vs baseline: 1.0514x; 1.0154x over previous
//
#include <hip/hip_runtime.h>
#include <hip/hip_bf16.h>

// CombinedGeomAttention, ALPHA=1:
//   s = 0.125*sqrt(relu(|q|^2|k|^2 - (q.k)^2) + 1e-8); out0 = softmax_s(s) @ V; out1 = mean(s)
// Round 6: ONE barrier per K/V tile (K+V both double-buffered; prefetch issued
// right after the barrier, drains at the next one). Compact swizzled P (40KB LDS,
// 4 blocks/CU, grid fully resident). Swapped-QK packed-f32 score path.

#define B_ 4
#define L_ 2048
#define S_ 2048
#define H_ 8
#define E_ 64
#define EPS_ 1e-8f
#define SC2_ 0.18033688011112042f   // 0.125 * log2(e)
#define LN2_ 0.6931471805599453f
#define ROWSTR (H_ * E_)            // 512 floats
#define NOUT ((size_t)B_ * L_ * H_ * E_)

#define K_OFF 0
#define V_OFF 8388608
#define KN_OFF 16777216
#define WS_NEED 17039360

typedef __attribute__((ext_vector_type(8))) short bf16x8;
typedef __attribute__((ext_vector_type(4))) float f32x4;
typedef __attribute__((ext_vector_type(2))) float f32x2;

union bfr8 { bf16x8 v; unsigned u[4]; };

static __device__ __forceinline__ unsigned pk2(float lo, float hi) {
  union { __hip_bfloat162 h2; unsigned u; } cv;
  cv.h2 = __float22bfloat162_rn(float2{lo, hi});
  return cv.u;
}
static __device__ __forceinline__ unsigned cvtpk(float lo, float hi) {
  unsigned r;
  asm("v_cvt_pk_bf16_f32 %0, %1, %2" : "=v"(r) : "v"(lo), "v"(hi));
  return r;
}
static __device__ __forceinline__ float fast_sqrt(float x) {
  float r; asm("v_sqrt_f32 %0, %1" : "=v"(r) : "v"(x)); return r;
}
static __device__ __forceinline__ float fast_exp2(float x) {
  float r; asm("v_exp_f32 %0, %1" : "=v"(r) : "v"(x)); return r;
}
static __device__ __forceinline__ void gload16(const void* g, void* l) {
  __builtin_amdgcn_global_load_lds((const __attribute__((address_space(1))) void*)g,
                                   (__attribute__((address_space(3))) void*)l, 16, 0, 0);
}

// ---------------- fused prepass: one block = one (bh, s-tile); does K AND V ----------------
// K -> bf16 swizzled [bh,tile][s][e-chunks] + |k|^2 ; V -> bf16 transposed+swizzled [e][s-chunks]
__global__ void prep_kv(const float* __restrict__ K, const float* __restrict__ V,
                        short* __restrict__ Kg, short* __restrict__ Vg,
                        float* __restrict__ kn2g, float* __restrict__ out) {
  const int tid = threadIdx.x;
  const int bidx = blockIdx.x;          // bh*32 + st
  if (bidx == 0 && tid == 0) out[NOUT] = 0.f;   // zero the scalar accumulator slot
  const int st = bidx & 31;
  const int bh = bidx >> 5;
  const int b = bh >> 3, h = bh & 7;
  const size_t src_base = (size_t)b * (L_ * ROWSTR) + (size_t)(st * 64) * ROWSTR + (size_t)h * E_;

  // ---- K part
  {
    short* dst = Kg + (size_t)bidx * 4096;
    const int s = tid >> 2;
    float part = 0.f;
#pragma unroll
    for (int q = 0; q < 2; ++q) {
      const int ch = (2 * tid + q) & 7;
      const int esrc = (ch ^ (s & 7)) * 8;
      const float* sp = K + src_base + (size_t)s * ROWSTR + esrc;
      const float4 a = *reinterpret_cast<const float4*>(sp);
      const float4 c4 = *reinterpret_cast<const float4*>(sp + 4);
      part += a.x*a.x + a.y*a.y + a.z*a.z + a.w*a.w
            + c4.x*c4.x + c4.y*c4.y + c4.z*c4.z + c4.w*c4.w;
      bfr8 o;
      o.u[0] = pk2(a.x, a.y);  o.u[1] = pk2(a.z, a.w);
      o.u[2] = pk2(c4.x, c4.y); o.u[3] = pk2(c4.z, c4.w);
      *reinterpret_cast<bf16x8*>(dst + s * 64 + ch * 8) = o.v;
    }
    part += __shfl_xor(part, 1);
    part += __shfl_xor(part, 2);
    if ((tid & 3) == 0) kn2g[(size_t)bidx * 64 + s] = part;
  }

  // ---- V part (no LDS; coalesced 256B column-segment reads)
  {
    short* dst = Vg + (size_t)bidx * 4096;
    const int e = tid & 63;
    const int sc0 = tid >> 6;       // 0..3; handles sc0 and sc0+4
#pragma unroll
    for (int q = 0; q < 2; ++q) {
      const int sc = sc0 + q * 4;
      const float* sp = V + src_base + (size_t)(sc * 8) * ROWSTR + e;
      const float v0 = sp[0];
      const float v1 = sp[1 * ROWSTR];
      const float v2 = sp[2 * ROWSTR];
      const float v3 = sp[3 * ROWSTR];
      const float v4 = sp[4 * ROWSTR];
      const float v5 = sp[5 * ROWSTR];
      const float v6 = sp[6 * ROWSTR];
      const float v7 = sp[7 * ROWSTR];
      bfr8 o;
      o.u[0] = pk2(v0, v1); o.u[1] = pk2(v2, v3);
      o.u[2] = pk2(v4, v5); o.u[3] = pk2(v6, v7);
      *reinterpret_cast<bf16x8*>(dst + e * 64 + ((sc ^ (e & 7)) * 8)) = o.v;
    }
  }
}

// ---------------- main attention ----------------
__launch_bounds__(256, 4)
__global__ void geom_attn(const float* __restrict__ Q,
                          const short* __restrict__ Kg,
                          const short* __restrict__ Vg,
                          const float* __restrict__ kn2g,
                          float* __restrict__ out) {
  __shared__ __align__(16) short Kl[2][4096];   // 16 KB
  __shared__ __align__(16) short Vl[2][4096];   // 16 KB
  __shared__ __align__(16) short Plds[4][1024]; //  8 KB (compact, swizzled)

  const int tid = threadIdx.x;
  const int lane = tid & 63;
  const int w = tid >> 6;       // 0..3
  const int g = lane >> 4;      // 0..3
  const int c = lane & 15;
  const int cx = c & 7;

  // XCD-chunked swizzle: 1024 blocks; each XCD owns 4 consecutive bh (K/V ~2MB in its L2)
  const int vbk = ((blockIdx.x & 7) << 7) + (blockIdx.x >> 3);
  const int qt = vbk & 31;
  const int bh = vbk >> 5;
  const int b = bh >> 3, h = bh & 7;
  const int q0 = qt * 64;

  const size_t qbase = (size_t)b * (L_ * ROWSTR) + (size_t)h * E_;

  // ---- Q fragments (bf16 pairs) + |q|^2 (fp32 exact); lane holds qn2 of q-row w*16+c
  bfr8 qa[2];
  float qn2sc;
  {
    const int qrow = q0 + w * 16 + c;
    const float* qp = Q + qbase + (size_t)qrow * ROWSTR;
    float qs = 0.f;
#pragma unroll
    for (int ch = 0; ch < 2; ++ch) {
      const float4 a = *reinterpret_cast<const float4*>(qp + ch * 32 + g * 8);
      const float4 b4 = *reinterpret_cast<const float4*>(qp + ch * 32 + g * 8 + 4);
      qa[ch].u[0] = pk2(a.x, a.y);  qa[ch].u[1] = pk2(a.z, a.w);
      qa[ch].u[2] = pk2(b4.x, b4.y); qa[ch].u[3] = pk2(b4.z, b4.w);
      qs += a.x*a.x + a.y*a.y + a.z*a.z + a.w*a.w
          + b4.x*b4.x + b4.y*b4.y + b4.z*b4.z + b4.w*b4.w;
    }
    qs += __shfl_xor(qs, 16);
    qs += __shfl_xor(qs, 32);
    qn2sc = qs;
  }
  const f32x2 qn2v = {qn2sc, qn2sc};
  const f32x2 eps2 = {EPS_, EPS_};
  const f32x2 sc2v = {SC2_, SC2_};

  f32x2 lsA = {0.f, 0.f}, lsB = {0.f, 0.f};   // softmax denom partials
  f32x2 ssA = {0.f, 0.f}, ssB = {0.f, 0.f};   // score-sum partials
  f32x4 o[4];
#pragma unroll
  for (int dt = 0; dt < 4; ++dt) o[dt] = (f32x4){0.f, 0.f, 0.f, 0.f};

  const char* Ksrc = (const char*)(Kg + (size_t)(bh * 32) * 4096);
  const char* Vsrc = (const char*)(Vg + (size_t)(bh * 32) * 4096);
  const float* knb = kn2g + (size_t)(bh * 32) * 64;

  const int wb = w * 2048;  // wave's byte range within an 8KB tile

  f32x4 kn_cur[4], kn_nx[4];
#pragma unroll
  for (int sub = 0; sub < 4; ++sub)
    kn_cur[sub] = *reinterpret_cast<const f32x4*>(knb + sub * 16 + g * 4);

  // prologue: stage K[0], V[0] into buffer 0
  gload16(Ksrc + wb + lane * 16,        (char*)&Kl[0][0] + wb);
  gload16(Ksrc + wb + 1024 + lane * 16, (char*)&Kl[0][0] + wb + 1024);
  gload16(Vsrc + wb + lane * 16,        (char*)&Vl[0][0] + wb);
  gload16(Vsrc + wb + 1024 + lane * 16, (char*)&Vl[0][0] + wb + 1024);

  for (int kt = 0; kt < 32; ++kt) {
    const int cb = kt & 1;
    const int nx = (kt + 1) & 31;     // wrap: harmless extra prefetch on last iter
    __syncthreads();   // full drain: K[kt],V[kt] staged; bufs cb^1 free (read last iter)

    // prefetch tile kt+1 (has the whole compute phase to land)
#pragma unroll
    for (int sub = 0; sub < 4; ++sub)
      kn_nx[sub] = *reinterpret_cast<const f32x4*>(knb + nx * 64 + sub * 16 + g * 4);
    const char* vs = Vsrc + (size_t)nx * 8192;
    gload16(vs + wb + lane * 16,        (char*)&Vl[cb ^ 1][0] + wb);
    gload16(vs + wb + 1024 + lane * 16, (char*)&Vl[cb ^ 1][0] + wb + 1024);
    const char* ks = Ksrc + (size_t)nx * 8192;
    gload16(ks + wb + lane * 16,        (char*)&Kl[cb ^ 1][0] + wb);
    gload16(ks + wb + 1024 + lane * 16, (char*)&Kl[cb ^ 1][0] + wb + 1024);
    __builtin_amdgcn_sched_barrier(0);  // pin prefetch issue before compute

    // ---- swapped QK^T: acc[i] = S[s = sub*16 + g*4 + i][qrow = w*16 + c]
#pragma unroll
    for (int sub = 0; sub < 4; ++sub) {
      f32x4 acc = (f32x4){0.f, 0.f, 0.f, 0.f};
#pragma unroll
      for (int ch = 0; ch < 2; ++ch) {
        const int idx = (sub * 16 + c) * 64 + (((ch * 4 + g) ^ cx) << 3);
        const bf16x8 kh8 = *reinterpret_cast<const bf16x8*>(&Kl[cb][idx]);
        acc = __builtin_amdgcn_mfma_f32_16x16x32_bf16(kh8, qa[ch].v, acc, 0, 0, 0);
      }
      // packed-f32 score math
      const f32x2 d0 = {acc[0], acc[1]};
      const f32x2 d1 = {acc[2], acc[3]};
      const f32x2 ka = {kn_cur[sub][0], kn_cur[sub][1]};
      const f32x2 kb = {kn_cur[sub][2], kn_cur[sub][3]};
      f32x2 w0 = -d0 * d0 + (qn2v * ka + eps2);
      f32x2 w1 = -d1 * d1 + (qn2v * kb + eps2);
      w0[0] = fmaxf(w0[0], EPS_); w0[1] = fmaxf(w0[1], EPS_);
      w1[0] = fmaxf(w1[0], EPS_); w1[1] = fmaxf(w1[1], EPS_);
      f32x2 s0 = {fast_sqrt(w0[0]), fast_sqrt(w0[1])};
      f32x2 s1 = {fast_sqrt(w1[0]), fast_sqrt(w1[1])};
      s0 *= sc2v; s1 *= sc2v;
      ssA += s0; ssB += s1;
      const f32x2 p0 = {fast_exp2(s0[0]), fast_exp2(s0[1])};
      const f32x2 p1 = {fast_exp2(s1[0]), fast_exp2(s1[1])};
      lsA += p0; lsB += p1;
      uint2 pw;
      pw.x = cvtpk(p0[0], p0[1]);
      pw.y = cvtpk(p1[0], p1[1]);
      // compact swizzled P store: q-row c, shorts (sub*16+g*4) ^ (cx<<3)  (<64)
      const int po = c * 64 + ((sub * 16 + g * 4) ^ (cx << 3));
      *reinterpret_cast<uint2*>(&Plds[w][po]) = pw;
    }

    // ---- PV: o[16x64] += P[16x64] @ V[64x64]  (wave-private P; V ready since barrier)
    __builtin_amdgcn_s_setprio(1);
#pragma unroll
    for (int ks2 = 0; ks2 < 2; ++ks2) {
      const int pr = c * 64 + ((ks2 * 32 + g * 8) ^ (cx << 3));
      const bf16x8 pa = *reinterpret_cast<const bf16x8*>(&Plds[w][pr]);
#pragma unroll
      for (int dt = 0; dt < 4; ++dt) {
        const int idx = (dt * 16 + c) * 64 + (((ks2 * 4 + g) ^ cx) << 3);
        const bf16x8 vb8 = *reinterpret_cast<const bf16x8*>(&Vl[cb][idx]);
        o[dt] = __builtin_amdgcn_mfma_f32_16x16x32_bf16(pa, vb8, o[dt], 0, 0, 0);
      }
    }
    __builtin_amdgcn_s_setprio(0);
#pragma unroll
    for (int sub = 0; sub < 4; ++sub) kn_cur[sub] = kn_nx[sub];
  }

  // ---- epilogue: finish row-c sum, broadcast row g*4+i's inverse, store
  const f32x2 lsT = lsA + lsB;
  float lsum = lsT[0] + lsT[1];
  lsum += __shfl_xor(lsum, 16);
  lsum += __shfl_xor(lsum, 32);
  const float rinv = 1.0f / lsum;   // 1/rowsum for q-row (w*16 + c)

#pragma unroll
  for (int i = 0; i < 4; ++i) {
    const float inv = __shfl(rinv, g * 4 + i);   // lane g*4+i holds row g*4+i
    const int qrow = q0 + w * 16 + g * 4 + i;
    float* op = out + (size_t)b * (L_ * ROWSTR) + (size_t)qrow * ROWSTR + (size_t)h * E_;
#pragma unroll
    for (int dt = 0; dt < 4; ++dt)
      op[dt * 16 + c] = o[dt][i] * inv;
  }

  const f32x2 ssT = ssA + ssB;
  float ssum = ssT[0] + ssT[1];
#pragma unroll
  for (int m = 1; m < 64; m <<= 1) ssum += __shfl_xor(ssum, m);
  if (lane == 0) atomicAdd(out + NOUT, ssum * (LN2_ / 134217728.0f));
}

extern "C" void kernel_launch(void* const* d_in, const int* in_sizes, int n_in,
                              void* d_out, int out_size, void* d_ws, size_t ws_size,
                              hipStream_t stream) {
  const float* Q = (const float*)d_in[0];
  const float* K = (const float*)d_in[1];
  const float* V = (const float*)d_in[2];
  float* out = (float*)d_out;

  short* Kg = (short*)((char*)d_ws + K_OFF);
  short* Vg = (short*)((char*)d_ws + V_OFF);
  float* kn2g = (float*)((char*)d_ws + KN_OFF);

  prep_kv<<<dim3(1024), dim3(256), 0, stream>>>(K, V, Kg, Vg, kn2g, out);
  geom_attn<<<dim3(1024), dim3(256), 0, stream>>>(Q, Kg, Vg, kn2g, out);
}